// Round 4
// baseline (74.064 us; speedup 1.0000x reference)
//
#include <hip/hip_runtime.h>

typedef unsigned short ushort_t;
typedef __attribute__((ext_vector_type(8))) __bf16 bf16x8;
typedef __attribute__((ext_vector_type(8))) short short8_t;
typedef __attribute__((ext_vector_type(4))) float f32x4;

#define C127 (127.0f / 128.0f)

__device__ inline ushort_t f2bf(float f) {
  unsigned u = __builtin_bit_cast(unsigned, f);
  u += 0x7fffu + ((u >> 16) & 1u);
  return (ushort_t)(u >> 16);
}

__device__ inline bf16x8 ldfrag(const ushort_t* p) {
  return __builtin_bit_cast(bf16x8, *(const short8_t*)p);
}

__device__ inline f32x4 mfma16(bf16x8 a, bf16x8 b, f32x4 c) {
  return __builtin_amdgcn_mfma_f32_16x16x32_bf16(a, b, c, 0, 0, 0);
}

// (row,col) -> position in 64-wide swizzled LDS/global tile
__device__ inline int swz(int row, int col) {
  return row * 64 + (col ^ ((row & 7) << 3));
}

__device__ inline void gl_lds16(const ushort_t* g, ushort_t* l) {
  __builtin_amdgcn_global_load_lds(
      (const __attribute__((address_space(1))) unsigned*)(g),
      (__attribute__((address_space(3))) unsigned*)(l),
      16, 0, 0);
}

// ================= unified prep =================
// regions (i = blockIdx*256+tid):
//  [0, 2359296)                 wft swizzled 64x64 tiles (R2 layout)
//  [2359296, 5505024)           xbt swizzled 128x64 tiles: [32 rowblk][12 kblk]
//  then per-8-elem regions:
//  xbt_f fragment-major (393216 thr), bfm frags (28672), w1b (8192), bias (32)
__global__ __launch_bounds__(256) void k_prep(
    const float* __restrict__ x,
    const float* Wp, const float* Wmi, const float* Wma, const float* Wd,
    const float* W1p, const float* W1mi, const float* W1ma, const float* W1d,
    const float* Wop, const float* Womi, const float* Woma, const float* Wod,
    const float* bop, const float* bomi, const float* boma, const float* bod,
    const float* Wc,
    ushort_t* wft, ushort_t* xbt, ushort_t* xbt_f, ushort_t* bfm,
    ushort_t* w1b, float* biassum)
{
  long long i = (long long)blockIdx.x * 256 + threadIdx.x;
  const long long R1 = 2359296, R2 = R1 + 3145728, R3 = R2 + 393216,
                  R4 = R3 + 28672, R5 = R4 + 8192, R6 = R5 + 32;
  if (i < R1) {
    int ii = (int)i;
    int jbase, d, nk; const float* src;
    if (ii < 262144)       { jbase = 0;       d = 128; nk = 2; src = Wp; }
    else if (ii < 786432)  { jbase = 262144;  d = 256; nk = 4; src = Wmi; }
    else if (ii < 1572864) { jbase = 786432;  d = 384; nk = 6; src = Wma; }
    else                   { jbase = 1572864; d = 384; nk = 6; src = Wd; }
    int j = ii - jbase;
    int tile = j >> 12, e = j & 4095;
    int rowtile = tile / nk, kblk = tile - rowtile * nk;
    int trow = e >> 6, scol = e & 63;
    int col = scol ^ ((trow & 7) << 3);
    wft[ii] = f2bf(src[(size_t)(rowtile * 64 + trow) * d + kblk * 64 + col]);
  } else if (i < R2) {
    int j = (int)(i - R1);
    int tile = j >> 13, e = j & 8191;
    int rowblk = tile / 12, kblk = tile - rowblk * 12;
    int trow = e >> 6, scol = e & 63;
    int col = scol ^ ((trow & 7) << 3);
    xbt[j] = f2bf(x[(size_t)(rowblk * 128 + trow) * 768 + kblk * 64 + col]);
  } else if (i < R3) {
    int j = (int)(i - R2);
    int tile = j >> 6, lane = j & 63;
    int rt = tile / 24, kc = tile - rt * 24;
    int row = rt * 16 + (lane & 15);
    int k = kc * 32 + (lane >> 4) * 8;
    const float* sp = x + (size_t)row * 768 + k;
    ushort_t tmp[8];
#pragma unroll
    for (int e = 0; e < 8; ++e) tmp[e] = f2bf(sp[e]);
    *(short8_t*)(xbt_f + (size_t)j * 8) = *(const short8_t*)tmp;
  } else if (i < R4) {
    int j = (int)(i - R3);
    int tile = j >> 6, lane = j & 63;
    int ct = tile / 28, kc = tile - ct * 28;
    int n = ct * 16 + (lane & 15);
    int c0 = kc * 32 + (lane >> 4) * 8;
    ushort_t tmp[8];
#pragma unroll
    for (int e = 0; e < 8; ++e) {
      int c = c0 + e;
      float v;
      if (c < 128) {
        int ss = c >> 5, jj2 = c & 31;
        const float* src = (ss == 0) ? Wop : (ss == 1) ? Womi : (ss == 2) ? Woma : Wod;
        v = src[n * 32 + jj2];
      } else {
        v = Wc[n * 768 + (c - 128)];
      }
      tmp[e] = f2bf(v);
    }
    *(short8_t*)(bfm + (size_t)j * 8) = *(const short8_t*)tmp;
  } else if (i < R5) {
    int j = (int)(i - R4);
    int s = j >> 11, r = j & 2047;
    const float* src = (s == 0) ? W1p : (s == 1) ? W1mi : (s == 2) ? W1ma : W1d;
    ushort_t tmp[8];
#pragma unroll
    for (int e = 0; e < 8; ++e) tmp[e] = f2bf(src[r * 8 + e]);
    *(short8_t*)(w1b + (size_t)j * 8) = *(const short8_t*)tmp;
  } else if (i < R6) {
    int j = (int)(i - R5);
#pragma unroll
    for (int e = 0; e < 8; ++e) {
      int n = j * 8 + e;
      biassum[n] = bop[n] + bomi[n] + boma[n] + bod[n];
    }
  }
}

// ================= ft GEMM (dbuf LDS, stage-ahead) + fused W1 =================
struct FtP {
  const ushort_t* xbt;
  const ushort_t* wft;
  const ushort_t* w1b;
  float* pf;   // [4 s][16 g][4096 rows][16 j]
  const float* bft0; const float* bft1; const float* bft2; const float* bft3;
};

__global__ __launch_bounds__(256) void k_ft(FtP p) {
  int b = blockIdx.x;
  int s, rem;
  if (b < 512)       { s = 2; rem = b; }
  else if (b < 1024) { s = 3; rem = b - 512; }
  else if (b < 1536) { s = 1; rem = b - 1024; }
  else               { s = 0; rem = b - 1536; }
  int g = rem & 15, rowblk = rem >> 4;

  int nk; int soff; const float* bft; unsigned long long ctbl;
  if (s == 0)      { nk = 2; soff = 0;       bft = p.bft0; ctbl = 0x60ULL; }
  else if (s == 1) { nk = 4; soff = 262144;  bft = p.bft1; ctbl = 0x8721ULL; }
  else if (s == 2) { nk = 6; soff = 786432;  bft = p.bft2; ctbl = 0xBA9543ULL; }
  else             { nk = 6; soff = 1572864; bft = p.bft3; ctbl = 0xBA8542ULL; }

  int row0 = rowblk * 128;
  int tid = threadIdx.x, lane = tid & 63, wid = tid >> 6;
  int wr = wid >> 1, wc = wid & 1;
  int lr = lane & 15, lk = (lane >> 4) * 8, lrow = (lane >> 4) * 4;

  __shared__ ushort_t lA[2][128 * 64];
  __shared__ ushort_t lB[2][2][64 * 64];

  const f32x4 fz = {0.f, 0.f, 0.f, 0.f};
  f32x4 acc[2][4][2];
#pragma unroll
  for (int h = 0; h < 2; ++h)
#pragma unroll
    for (int m = 0; m < 4; ++m)
#pragma unroll
      for (int n = 0; n < 2; ++n) acc[h][m][n] = fz;

#define STG(bufi, ks_)                                                       \
  {                                                                          \
    int ch_ = (int)((ctbl >> (4 * (ks_))) & 15ULL);                          \
    const ushort_t* at_  = p.xbt + ((size_t)rowblk * 12 + ch_) * 8192;       \
    const ushort_t* b1t_ = p.wft + soff + ((size_t)(g * nk + (ks_))) * 4096; \
    const ushort_t* b2t_ =                                                   \
        p.wft + soff + ((size_t)((16 + g) * nk + (ks_))) * 4096;             \
    _Pragma("unroll") for (int c = 0; c < 4; ++c) {                          \
      int off = (c * 4 + wid) * 512;                                         \
      gl_lds16(at_ + off + lane * 8, &lA[bufi][off]);                        \
    }                                                                        \
    _Pragma("unroll") for (int c = 0; c < 2; ++c) {                          \
      int off = (c * 4 + wid) * 512;                                         \
      gl_lds16(b1t_ + off + lane * 8, &lB[bufi][0][off]);                    \
      gl_lds16(b2t_ + off + lane * 8, &lB[bufi][1][off]);                    \
    }                                                                        \
  }

  STG(0, 0);
  __syncthreads();
  for (int t = 0; t < nk; ++t) {
    int cur = t & 1;
    if (t + 1 < nk) STG((t + 1) & 1, t + 1);
#pragma unroll
    for (int kk = 0; kk < 64; kk += 32) {
      bf16x8 a[4], bb[2][2];
#pragma unroll
      for (int m = 0; m < 4; ++m)
        a[m] = ldfrag(&lA[cur][swz(wr * 64 + m * 16 + lr, kk + lk)]);
#pragma unroll
      for (int h = 0; h < 2; ++h)
#pragma unroll
        for (int n = 0; n < 2; ++n)
          bb[h][n] = ldfrag(&lB[cur][h][swz(wc * 32 + n * 16 + lr, kk + lk)]);
#pragma unroll
      for (int h = 0; h < 2; ++h)
#pragma unroll
        for (int m = 0; m < 4; ++m)
#pragma unroll
          for (int n = 0; n < 2; ++n)
            acc[h][m][n] = mfma16(a[m], bb[h][n], acc[h][m][n]);
    }
    __syncthreads();
  }
#undef STG

  // epilogue: activation -> lA[nk&1] (not read by last compute), W1 partial
  ushort_t* act = lA[nk & 1];
#pragma unroll
  for (int m = 0; m < 4; ++m)
#pragma unroll
    for (int n = 0; n < 2; ++n) {
      int col = wc * 32 + n * 16 + lr;
      float bb1 = bft[g * 64 + col];
      float bb2 = bft[1024 + g * 64 + col];
#pragma unroll
      for (int r = 0; r < 4; ++r) {
        int row = wr * 64 + m * 16 + lrow + r;
        float v = (acc[0][m][n][r] + bb1) * (acc[1][m][n][r] + bb2) * C127;
        act[swz(row, col)] = f2bf(v);
      }
    }
  __syncthreads();

  const ushort_t* w1base = p.w1b + s * 16384 + lr * 1024 + g * 64 + lk;
  bf16x8 bw0 = ldfrag(w1base);
  bf16x8 bw1 = ldfrag(w1base + 32);
#pragma unroll
  for (int rt = 0; rt < 2; ++rt) {
    int rowbase = wid * 32 + rt * 16;
    f32x4 af = {0.f, 0.f, 0.f, 0.f};
    bf16x8 fa0 = ldfrag(&act[swz(rowbase + lr, 0 + lk)]);
    bf16x8 fa1 = ldfrag(&act[swz(rowbase + lr, 32 + lk)]);
    af = mfma16(fa0, bw0, af);
    af = mfma16(fa1, bw1, af);
    float* pfp =
        p.pf + ((size_t)(s * 16 + g) * 4096 + row0 + rowbase + lrow) * 16 + lr;
#pragma unroll
    for (int r = 0; r < 4; ++r) pfp[r * 16] = af[r];
  }
}

// ================= reduce partials -> cat (fragment-major) =================
__global__ __launch_bounds__(256) void k_fin(
    const float* __restrict__ pf, ushort_t* __restrict__ cat_t,
    const float* b1p, const float* b1mi, const float* b1ma, const float* b1d)
{
  int tid = threadIdx.x;
  int j = tid & 15, s = (tid >> 4) & 3, rl = tid >> 6;
  int row = blockIdx.x * 4 + rl;
  const float* b1 = (s == 0) ? b1p : (s == 1) ? b1mi : (s == 2) ? b1ma : b1d;
  float acc = 0.f;
  const float* base = pf + (size_t)(s * 16) * 65536 + (size_t)row * 16 + j;
#pragma unroll
  for (int nb = 0; nb < 16; ++nb) acc += base[(size_t)nb * 65536];
  float f = acc + b1[j];
  float cf = fminf(fmaxf(f, 0.f), 1.f);
  float cs = fminf(f * f * C127, 1.f);
  int rt = row >> 4, rl16 = row & 15;
  int c1 = s * 32 + j;
  {
    int kc = c1 >> 5, lane2 = rl16 + (((c1 >> 3) & 3) << 4), e = c1 & 7;
    cat_t[(size_t)(rt * 4 + kc) * 512 + lane2 * 8 + e] = f2bf(cf);
  }
  {
    int c2 = c1 + 16;
    int kc = c2 >> 5, lane2 = rl16 + (((c2 >> 3) & 3) << 4), e = c2 & 7;
    cat_t[(size_t)(rt * 4 + kc) * 512 + lane2 * 8 + e] = f2bf(cs);
  }
}

// ================= final GEMM (fragment streaming, barrier-free) =================
__global__ __launch_bounds__(256) void k_out(
    const ushort_t* __restrict__ cat_t, const ushort_t* __restrict__ xbt_f,
    const ushort_t* __restrict__ bfm, const float* __restrict__ biassum,
    float* __restrict__ out)
{
  int by = blockIdx.y, bx = blockIdx.x;
  int tid = threadIdx.x, lane = tid & 63, wid = tid >> 6;
  int wr = wid >> 1, wc = wid & 1;
  int lr = lane & 15, lrow = (lane >> 4) * 4;

  const ushort_t* Acat[4];
  const ushort_t* Ax[4];
#pragma unroll
  for (int m = 0; m < 4; ++m) {
    int rt = by * 8 + wr * 4 + m;
    Acat[m] = cat_t + (size_t)(rt * 4) * 512 + lane * 8;
    Ax[m]   = xbt_f + (size_t)(rt * 24) * 512 + lane * 8;
  }
  const ushort_t* Bb[2];
#pragma unroll
  for (int n = 0; n < 2; ++n)
    Bb[n] = bfm + (size_t)((bx * 4 + wc * 2 + n) * 28) * 512 + lane * 8;

  const f32x4 fz = {0.f, 0.f, 0.f, 0.f};
  f32x4 acc[4][2];
#pragma unroll
  for (int m = 0; m < 4; ++m)
#pragma unroll
    for (int n = 0; n < 2; ++n) acc[m][n] = fz;

  bf16x8 a0[4], a1[4], b0[2], b1[2];

#define LOADSET2(A, B, t)                                                  \
  {                                                                        \
    int t_ = (t);                                                          \
    _Pragma("unroll") for (int m = 0; m < 4; ++m)                          \
        A[m] = (t_ < 4) ? ldfrag(Acat[m] + (size_t)t_ * 512)               \
                        : ldfrag(Ax[m] + (size_t)(t_ - 4) * 512);          \
    _Pragma("unroll") for (int n = 0; n < 2; ++n)                          \
        B[n] = ldfrag(Bb[n] + (size_t)t_ * 512);                           \
  }
#define MFMASET2(A, B)                                                     \
  _Pragma("unroll") for (int m = 0; m < 4; ++m)                            \
      _Pragma("unroll") for (int n = 0; n < 2; ++n)                        \
          acc[m][n] = mfma16(A[m], B[n], acc[m][n]);

  LOADSET2(a0, b0, 0);
  for (int tt = 0; tt < 14; ++tt) {
    LOADSET2(a1, b1, 2 * tt + 1);
    MFMASET2(a0, b0);
    int t2 = 2 * tt + 2; if (t2 >= 28) t2 = 27;
    LOADSET2(a0, b0, t2);
    MFMASET2(a1, b1);
  }
#undef LOADSET2
#undef MFMASET2

#pragma unroll
  for (int m = 0; m < 4; ++m)
#pragma unroll
    for (int n = 0; n < 2; ++n) {
      int col = bx * 64 + wc * 32 + n * 16 + lr;
      float bs = biassum[col];
#pragma unroll
      for (int r = 0; r < 4; ++r) {
        int row = by * 128 + wr * 64 + m * 16 + lrow + r;
        out[(size_t)row * 256 + col] = acc[m][n][r] + bs;
      }
    }
}

extern "C" void kernel_launch(void* const* d_in, const int* in_sizes, int n_in,
                              void* d_out, int out_size, void* d_ws, size_t ws_size,
                              hipStream_t stream)
{
  const float* x     = (const float*)d_in[0];
  const float* pWft  = (const float*)d_in[5];   const float* pbft  = (const float*)d_in[6];
  const float* pW1   = (const float*)d_in[7];   const float* pb1   = (const float*)d_in[8];
  const float* pWo   = (const float*)d_in[9];   const float* pbo   = (const float*)d_in[10];
  const float* miWft = (const float*)d_in[11];  const float* mibft = (const float*)d_in[12];
  const float* miW1  = (const float*)d_in[13];  const float* mib1  = (const float*)d_in[14];
  const float* miWo  = (const float*)d_in[15];  const float* mibo  = (const float*)d_in[16];
  const float* maWft = (const float*)d_in[17];  const float* mabft = (const float*)d_in[18];
  const float* maW1  = (const float*)d_in[19];  const float* mab1  = (const float*)d_in[20];
  const float* maWo  = (const float*)d_in[21];  const float* mabo  = (const float*)d_in[22];
  const float* dWft  = (const float*)d_in[23];  const float* dbft  = (const float*)d_in[24];
  const float* dW1   = (const float*)d_in[25];  const float* db1   = (const float*)d_in[26];
  const float* dWo   = (const float*)d_in[27];  const float* dbo   = (const float*)d_in[28];
  const float* Wc    = (const float*)d_in[29];

  char* wsb = (char*)d_ws;
  ushort_t* xbt     = (ushort_t*)(wsb + 0);          // 6,291,456
  ushort_t* xbt_f   = (ushort_t*)(wsb + 6291456);    // 6,291,456
  ushort_t* wft     = (ushort_t*)(wsb + 12582912);   // 4,718,592
  ushort_t* w1b     = (ushort_t*)(wsb + 17301504);   //   131,072
  ushort_t* bfm     = (ushort_t*)(wsb + 17432576);   //   458,752
  float*    biassum = (float*)(wsb + 17891328);      //     1,024
  float*    pf      = (float*)(wsb + 17892352);      // 16,777,216
  ushort_t* cat_t   = (ushort_t*)(wsb + 34669568);   // 1,048,576

  k_prep<<<dim3(23185), dim3(256), 0, stream>>>(
      x, pWft, miWft, maWft, dWft, pW1, miW1, maW1, dW1,
      pWo, miWo, maWo, dWo, pbo, mibo, mabo, dbo, Wc,
      wft, xbt, xbt_f, bfm, w1b, biassum);

  FtP fp;
  fp.xbt = xbt; fp.wft = wft; fp.w1b = w1b; fp.pf = pf;
  fp.bft0 = pbft; fp.bft1 = mibft; fp.bft2 = mabft; fp.bft3 = dbft;
  k_ft<<<dim3(2048), dim3(256), 0, stream>>>(fp);

  k_fin<<<dim3(1024), dim3(256), 0, stream>>>(pf, cat_t, pb1, mib1, mab1, db1);

  k_out<<<dim3(4, 32), dim3(256), 0, stream>>>(cat_t, xbt_f, bfm, biassum, (float*)d_out);
}

// Round 5
// 58.996 us; speedup vs baseline: 1.2554x; 1.2554x over previous
//
#include <hip/hip_runtime.h>

typedef unsigned short ushort_t;
typedef __attribute__((ext_vector_type(8))) __bf16 bf16x8;
typedef __attribute__((ext_vector_type(8))) short short8_t;
typedef __attribute__((ext_vector_type(4))) float f32x4;

#define C127 (127.0f / 128.0f)

__device__ inline ushort_t f2bf(float f) {
  unsigned u = __builtin_bit_cast(unsigned, f);
  u += 0x7fffu + ((u >> 16) & 1u);
  return (ushort_t)(u >> 16);
}

__device__ inline bf16x8 ldfrag(const ushort_t* p) {
  return __builtin_bit_cast(bf16x8, *(const short8_t*)p);
}

__device__ inline f32x4 mfma16(bf16x8 a, bf16x8 b, f32x4 c) {
  return __builtin_amdgcn_mfma_f32_16x16x32_bf16(a, b, c, 0, 0, 0);
}

// (row,col) -> position in 64-wide swizzled tile
__device__ inline int swz(int row, int col) {
  return row * 64 + (col ^ ((row & 7) << 3));
}

__device__ inline void gl_lds16(const ushort_t* g, ushort_t* l) {
  __builtin_amdgcn_global_load_lds(
      (const __attribute__((address_space(1))) unsigned*)(g),
      (__attribute__((address_space(3))) unsigned*)(l),
      16, 0, 0);
}

// ================= prep: fully vectorized (16B per thread) =================
// wft: per s: [32 rowtiles][nk kblks][64x64 swz]   (294912 thr-units)
// xbt: [32 rowblk][12 kblk][128x64 swz]            (393216)
// bfm: [8 nb][14 kblk][32x64 swz]                  (28672)
// w1b: row-major [4][16][1024]                     (8192)
// bias                                             (32)
__global__ __launch_bounds__(256) void k_prep(
    const float* __restrict__ x,
    const float* Wp, const float* Wmi, const float* Wma, const float* Wd,
    const float* W1p, const float* W1mi, const float* W1ma, const float* W1d,
    const float* Wop, const float* Womi, const float* Woma, const float* Wod,
    const float* bop, const float* bomi, const float* boma, const float* bod,
    const float* Wc,
    ushort_t* wft, ushort_t* xbt, ushort_t* bfm, ushort_t* w1b, float* biassum)
{
  int i = blockIdx.x * 256 + threadIdx.x;
  const int RW = 294912, RX = RW + 393216, RB = RX + 28672, R1 = RB + 8192,
            RE = R1 + 32;
  if (i < RW) {
    const float* src; int base, d, nk;
    if (i < 32768)       { base = 0;      d = 128; nk = 2; src = Wp; }
    else if (i < 98304)  { base = 32768;  d = 256; nk = 4; src = Wmi; }
    else if (i < 196608) { base = 98304;  d = 384; nk = 6; src = Wma; }
    else                 { base = 196608; d = 384; nk = 6; src = Wd; }
    int jl = i - base;
    int tile = jl >> 9, trow = (jl & 511) >> 3, scol0 = (jl & 7) * 8;
    int rowtile = tile / nk, kblk = tile - rowtile * nk;
    int col0 = scol0 ^ ((trow & 7) << 3);
    const float* sp = src + (size_t)(rowtile * 64 + trow) * d + kblk * 64 + col0;
    ushort_t tmp[8];
#pragma unroll
    for (int e = 0; e < 8; ++e) tmp[e] = f2bf(sp[e]);
    *(short8_t*)(wft + (size_t)i * 8) = *(const short8_t*)tmp;
  } else if (i < RX) {
    int i2 = i - RW;
    int tile = i2 >> 10, trow = (i2 & 1023) >> 3, scol0 = (i2 & 7) * 8;
    int rowblk = tile / 12, kblk = tile - rowblk * 12;
    int col0 = scol0 ^ ((trow & 7) << 3);
    const float* sp = x + (size_t)(rowblk * 128 + trow) * 768 + kblk * 64 + col0;
    ushort_t tmp[8];
#pragma unroll
    for (int e = 0; e < 8; ++e) tmp[e] = f2bf(sp[e]);
    *(short8_t*)(xbt + (size_t)i2 * 8) = *(const short8_t*)tmp;
  } else if (i < RB) {
    int i3 = i - RX;
    int tile = i3 >> 8, trow = (i3 & 255) >> 3, scol0 = (i3 & 7) * 8;
    int nb = tile / 14, kblk = tile - nb * 14;
    int col0 = scol0 ^ ((trow & 7) << 3);
    int n = nb * 32 + trow, c0 = kblk * 64 + col0;
    const float* sp;
    if (c0 < 128) {
      int ss = c0 >> 5, jj = c0 & 31;
      const float* src = (ss == 0) ? Wop : (ss == 1) ? Womi : (ss == 2) ? Woma : Wod;
      sp = src + n * 32 + jj;
    } else {
      sp = Wc + n * 768 + (c0 - 128);
    }
    ushort_t tmp[8];
#pragma unroll
    for (int e = 0; e < 8; ++e) tmp[e] = f2bf(sp[e]);
    *(short8_t*)(bfm + (size_t)i3 * 8) = *(const short8_t*)tmp;
  } else if (i < R1) {
    int i4 = i - RB;
    int s = i4 >> 11, r = i4 & 2047;
    const float* src = (s == 0) ? W1p : (s == 1) ? W1mi : (s == 2) ? W1ma : W1d;
    ushort_t tmp[8];
#pragma unroll
    for (int e = 0; e < 8; ++e) tmp[e] = f2bf(src[r * 8 + e]);
    *(short8_t*)(w1b + (size_t)i4 * 8) = *(const short8_t*)tmp;
  } else if (i < RE) {
    int i5 = i - R1;
#pragma unroll
    for (int e = 0; e < 8; ++e) {
      int n = i5 * 8 + e;
      biassum[n] = bop[n] + bomi[n] + boma[n] + bod[n];
    }
  }
}

// ================= ft GEMM: 8 waves, dbuf, 2 g per block =================
struct FtP {
  const ushort_t* xbt;
  const ushort_t* wft;
  const ushort_t* w1b;
  float* pf;   // [4 s][16 g][4096 rows][16 j]
  const float* bft0; const float* bft1; const float* bft2; const float* bft3;
};

__global__ __launch_bounds__(512, 4) void k_ft(FtP p) {
  int b = blockIdx.x;
  int s, rem;
  if (b < 256)      { s = 2; rem = b; }
  else if (b < 512) { s = 3; rem = b - 256; }
  else if (b < 768) { s = 1; rem = b - 512; }
  else              { s = 0; rem = b - 768; }
  int gp = rem & 7, rowblk = rem >> 3;
  int g0 = gp * 2;

  int nk; int soff; const float* bft; unsigned long long ctbl;
  if (s == 0)      { nk = 2; soff = 0;       bft = p.bft0; ctbl = 0x60ULL; }
  else if (s == 1) { nk = 4; soff = 262144;  bft = p.bft1; ctbl = 0x8721ULL; }
  else if (s == 2) { nk = 6; soff = 786432;  bft = p.bft2; ctbl = 0xBA9543ULL; }
  else             { nk = 6; soff = 1572864; bft = p.bft3; ctbl = 0xBA8542ULL; }

  int row0 = rowblk * 128;
  int tid = threadIdx.x, lane = tid & 63, wid = tid >> 6;
  int wr = wid >> 1, wc = wid & 1;
  int lr = lane & 15, lk = (lane >> 4) * 8, lrow = (lane >> 4) * 4;

  __shared__ ushort_t lA[2][8192];
  __shared__ ushort_t lB[2][2][4096];

  f32x4 acc[2][2][2];

#define STG(bufi, g_, ks_)                                                     \
  {                                                                            \
    int ch_ = (int)((ctbl >> (4 * (ks_))) & 15ULL);                            \
    const ushort_t* at_ = p.xbt + ((size_t)rowblk * 12 + ch_) * 8192;          \
    const ushort_t* b1t_ = p.wft + soff + ((size_t)((g_)*nk + (ks_))) * 4096;  \
    const ushort_t* b2t_ =                                                     \
        p.wft + soff + ((size_t)((16 + (g_)) * nk + (ks_))) * 4096;            \
    { int off = wid * 512; gl_lds16(at_ + off + lane * 8, &lA[bufi][off]); }   \
    { int off = (8 + wid) * 512;                                               \
      gl_lds16(at_ + off + lane * 8, &lA[bufi][off]); }                        \
    { int off = wid * 512;                                                     \
      gl_lds16(b1t_ + off + lane * 8, &lB[bufi][0][off]);                      \
      gl_lds16(b2t_ + off + lane * 8, &lB[bufi][1][off]); }                    \
  }

#pragma unroll
  for (int gg = 0; gg < 2; ++gg) {
    int g = g0 + gg;
#pragma unroll
    for (int h = 0; h < 2; ++h)
#pragma unroll
      for (int m = 0; m < 2; ++m)
#pragma unroll
        for (int n = 0; n < 2; ++n) acc[h][m][n] = (f32x4){0.f, 0.f, 0.f, 0.f};

    if (gg == 0) {
      STG(0, g, 0);
      __syncthreads();
    }
    // (for gg==1, buf0 was pre-staged during gg==0's epilogue)

    for (int t = 0; t < nk; ++t) {
      int cur = t & 1;
      if (t + 1 < nk) STG((t + 1) & 1, g, t + 1);
#pragma unroll
      for (int kk = 0; kk < 64; kk += 32) {
        bf16x8 a[2], bb[2][2];
#pragma unroll
        for (int m = 0; m < 2; ++m)
          a[m] = ldfrag(&lA[cur][swz(wr * 32 + m * 16 + lr, kk + lk)]);
#pragma unroll
        for (int h = 0; h < 2; ++h)
#pragma unroll
          for (int n = 0; n < 2; ++n)
            bb[h][n] = ldfrag(&lB[cur][h][swz(wc * 32 + n * 16 + lr, kk + lk)]);
#pragma unroll
        for (int h = 0; h < 2; ++h)
#pragma unroll
          for (int m = 0; m < 2; ++m)
#pragma unroll
            for (int n = 0; n < 2; ++n)
              acc[h][m][n] = mfma16(a[m], bb[h][n], acc[h][m][n]);
      }
      __syncthreads();
    }

    // prologue of next g overlaps this epilogue (nk even -> act uses lA[1])
    if (gg == 0) STG(0, g0 + 1, 0);

    ushort_t* act = lA[1];
#pragma unroll
    for (int m = 0; m < 2; ++m)
#pragma unroll
      for (int n = 0; n < 2; ++n) {
        int col = wc * 32 + n * 16 + lr;
        float bb1 = bft[g * 64 + col];
        float bb2 = bft[1024 + g * 64 + col];
#pragma unroll
        for (int r = 0; r < 4; ++r) {
          int row = wr * 32 + m * 16 + lrow + r;
          float v = (acc[0][m][n][r] + bb1) * (acc[1][m][n][r] + bb2) * C127;
          act[swz(row, col)] = f2bf(v);
        }
      }
    __syncthreads();

    const ushort_t* w1base = p.w1b + s * 16384 + lr * 1024 + g * 64 + lk;
    bf16x8 bw0 = ldfrag(w1base);
    bf16x8 bw1 = ldfrag(w1base + 32);
    int rowbase = wid * 16;
    f32x4 af = {0.f, 0.f, 0.f, 0.f};
    bf16x8 fa0 = ldfrag(&act[swz(rowbase + lr, 0 + lk)]);
    bf16x8 fa1 = ldfrag(&act[swz(rowbase + lr, 32 + lk)]);
    af = mfma16(fa0, bw0, af);
    af = mfma16(fa1, bw1, af);
    float* pfp =
        p.pf + ((size_t)(s * 16 + g) * 4096 + row0 + rowbase + lrow) * 16 + lr;
#pragma unroll
    for (int r = 0; r < 4; ++r) pfp[r * 16] = af[r];
    __syncthreads();
  }
#undef STG
}

// ================= reduce partials -> cat (tiled-swizzled) =================
__global__ __launch_bounds__(256) void k_fin(
    const float* __restrict__ pf, ushort_t* __restrict__ cat_t,
    const float* b1p, const float* b1mi, const float* b1ma, const float* b1d)
{
  int tid = threadIdx.x;
  int j = tid & 15, s = (tid >> 4) & 3, rl = tid >> 6;
  int row = blockIdx.x * 4 + rl;
  const float* b1 = (s == 0) ? b1p : (s == 1) ? b1mi : (s == 2) ? b1ma : b1d;
  float acc = 0.f;
  const float* base = pf + (size_t)(s * 16) * 65536 + (size_t)row * 16 + j;
#pragma unroll
  for (int nb = 0; nb < 16; ++nb) acc += base[(size_t)nb * 65536];
  float f = acc + b1[j];
  float cf = fminf(fmaxf(f, 0.f), 1.f);
  float cs = fminf(f * f * C127, 1.f);
  int trow = row & 127, rowblk = row >> 7;
  int c1 = s * 32 + j;
  {
    int kb = c1 >> 6, tc = c1 & 63;
    cat_t[(size_t)(rowblk * 2 + kb) * 8192 + trow * 64 + (tc ^ ((trow & 7) << 3))] =
        f2bf(cf);
  }
  {
    int c2 = c1 + 16;
    int kb = c2 >> 6, tc = c2 & 63;
    cat_t[(size_t)(rowblk * 2 + kb) * 8192 + trow * 64 + (tc ^ ((trow & 7) << 3))] =
        f2bf(cs);
  }
}

// ================= final GEMM: [cat | x] @ [WoAll|Wc]^T + biassum =================
__global__ __launch_bounds__(256) void k_out(
    const ushort_t* __restrict__ cat_t, const ushort_t* __restrict__ xbt,
    const ushort_t* __restrict__ bfm, const float* __restrict__ biassum,
    float* __restrict__ out)
{
  int rowblk = blockIdx.y, row0 = rowblk * 128;
  int nb = blockIdx.x;  // 8 x 32 cols
  int tid = threadIdx.x, lane = tid & 63, wid = tid >> 6;
  int lr = lane & 15, lk = (lane >> 4) * 8, lrow = (lane >> 4) * 4;

  __shared__ ushort_t lA[128 * 64];
  __shared__ ushort_t lB[32 * 64];

  const f32x4 fz = {0.f, 0.f, 0.f, 0.f};
  f32x4 acc[2][2];
#pragma unroll
  for (int m = 0; m < 2; ++m)
#pragma unroll
    for (int n = 0; n < 2; ++n) acc[m][n] = fz;

  for (int kb = 0; kb < 14; ++kb) {
    const ushort_t* at = (kb < 2)
        ? cat_t + ((size_t)rowblk * 2 + kb) * 8192
        : xbt + ((size_t)rowblk * 12 + (kb - 2)) * 8192;
    const ushort_t* bt = bfm + ((size_t)nb * 14 + kb) * 2048;
#pragma unroll
    for (int c = 0; c < 4; ++c) {
      int off = (c * 4 + wid) * 512;
      gl_lds16(at + off + lane * 8, &lA[off]);
    }
    {
      int off = wid * 512;
      gl_lds16(bt + off + lane * 8, &lB[off]);
    }
    __syncthreads();
#pragma unroll
    for (int kk = 0; kk < 64; kk += 32) {
      bf16x8 b0 = ldfrag(&lB[swz(lr, kk + lk)]);
      bf16x8 b1v = ldfrag(&lB[swz(16 + lr, kk + lk)]);
#pragma unroll
      for (int m = 0; m < 2; ++m) {
        bf16x8 a = ldfrag(&lA[swz(wid * 32 + m * 16 + lr, kk + lk)]);
        acc[m][0] = mfma16(a, b0, acc[m][0]);
        acc[m][1] = mfma16(a, b1v, acc[m][1]);
      }
    }
    __syncthreads();
  }

#pragma unroll
  for (int m = 0; m < 2; ++m)
#pragma unroll
    for (int n = 0; n < 2; ++n) {
      int col = nb * 32 + n * 16 + lr;
      float bs = biassum[col];
#pragma unroll
      for (int r = 0; r < 4; ++r) {
        int row = wid * 32 + m * 16 + lrow + r;
        out[(size_t)(row0 + row) * 256 + col] = acc[m][n][r] + bs;
      }
    }
}

extern "C" void kernel_launch(void* const* d_in, const int* in_sizes, int n_in,
                              void* d_out, int out_size, void* d_ws, size_t ws_size,
                              hipStream_t stream)
{
  const float* x     = (const float*)d_in[0];
  const float* pWft  = (const float*)d_in[5];   const float* pbft  = (const float*)d_in[6];
  const float* pW1   = (const float*)d_in[7];   const float* pb1   = (const float*)d_in[8];
  const float* pWo   = (const float*)d_in[9];   const float* pbo   = (const float*)d_in[10];
  const float* miWft = (const float*)d_in[11];  const float* mibft = (const float*)d_in[12];
  const float* miW1  = (const float*)d_in[13];  const float* mib1  = (const float*)d_in[14];
  const float* miWo  = (const float*)d_in[15];  const float* mibo  = (const float*)d_in[16];
  const float* maWft = (const float*)d_in[17];  const float* mabft = (const float*)d_in[18];
  const float* maW1  = (const float*)d_in[19];  const float* mab1  = (const float*)d_in[20];
  const float* maWo  = (const float*)d_in[21];  const float* mabo  = (const float*)d_in[22];
  const float* dWft  = (const float*)d_in[23];  const float* dbft  = (const float*)d_in[24];
  const float* dW1   = (const float*)d_in[25];  const float* db1   = (const float*)d_in[26];
  const float* dWo   = (const float*)d_in[27];  const float* dbo   = (const float*)d_in[28];
  const float* Wc    = (const float*)d_in[29];

  char* wsb = (char*)d_ws;
  ushort_t* xbt     = (ushort_t*)(wsb + 0);          //  6,291,456
  ushort_t* wft     = (ushort_t*)(wsb + 6291456);    //  4,718,592
  ushort_t* w1b     = (ushort_t*)(wsb + 11010048);   //    131,072
  ushort_t* bfm     = (ushort_t*)(wsb + 11141120);   //    458,752
  float*    biassum = (float*)(wsb + 11599872);      //      1,024
  float*    pf      = (float*)(wsb + 11600896);      // 16,777,216
  ushort_t* cat_t   = (ushort_t*)(wsb + 28378112);   //  1,048,576

  k_prep<<<dim3(2833), dim3(256), 0, stream>>>(
      x, pWft, miWft, maWft, dWft, pW1, miW1, maW1, dW1,
      pWo, miWo, maWo, dWo, pbo, mibo, mabo, dbo, Wc,
      wft, xbt, bfm, w1b, biassum);

  FtP fp;
  fp.xbt = xbt; fp.wft = wft; fp.w1b = w1b; fp.pf = pf;
  fp.bft0 = pbft; fp.bft1 = mibft; fp.bft2 = mabft; fp.bft3 = dbft;
  k_ft<<<dim3(1024), dim3(512), 0, stream>>>(fp);

  k_fin<<<dim3(1024), dim3(256), 0, stream>>>(pf, cat_t, pb1, mib1, mab1, db1);

  k_out<<<dim3(8, 32), dim3(256), 0, stream>>>(cat_t, xbt, bfm, biassum, (float*)d_out);
}